// Round 6
// baseline (1010.798 us; speedup 1.0000x reference)
//
#include <hip/hip_runtime.h>

#define NUM_USERS 100000
#define NUM_ITEMS 50000
#define N_NODES   150000   // NUM_USERS + NUM_ITEMS
#define DIM       64
#define NNZ       1000000
#define BATCH     4096

#define BROWS  240                    // rows per bucket (625 * 240 == 150000 exactly)
#define NBUCK  (N_NODES / BROWS)      // 625
#define NWG    256                    // workgroups in count/scatter
#define CHUNK  ((NNZ + NWG - 1) / NWG)// 3907 edges per WG
#define SCAN_N (NBUCK * NWG)          // 160000
#define SCAN_B 512
#define NBLK_S ((SCAN_N + SCAN_B - 1) / SCAN_B)  // 313

typedef unsigned int uint32;

// bf16 helpers (RNE convert, cheap expand)
__device__ __forceinline__ ushort f2bf(float f) {
    uint32 u = __float_as_uint(f);
    u += 0x7FFFu + ((u >> 16) & 1u);
    return (ushort)(u >> 16);
}
__device__ __forceinline__ float bf2f(ushort u) {
    return __uint_as_float(((uint32)u) << 16);
}

// ---------------------------------------------------------------------------
// count: per-WG histogram of bucket occupancy. cntArr[b*NWG + wg] = count of
// edges in WG wg's chunk that fall in bucket b. (bucket-major for the scan)
// ---------------------------------------------------------------------------
__global__ __launch_bounds__(256) void count_kernel(const int* __restrict__ rows,
                                                    int* __restrict__ cntArr) {
    __shared__ int h[NBUCK];
    for (int k = threadIdx.x; k < NBUCK; k += 256) h[k] = 0;
    __syncthreads();
    int lo = blockIdx.x * CHUNK, hi = min(NNZ, lo + CHUNK);
    for (int e = lo + threadIdx.x; e < hi; e += 256)
        atomicAdd(&h[rows[e] / BROWS], 1);
    __syncthreads();
    for (int k = threadIdx.x; k < NBUCK; k += 256)
        cntArr[k * NWG + blockIdx.x] = h[k];
}

// ---------------------------------------------------------------------------
// scan step A: per-block exclusive scan (512/block); blksum <- block total
// ---------------------------------------------------------------------------
__global__ __launch_bounds__(SCAN_B) void scan_block_kernel(
        const int* __restrict__ in, int* __restrict__ out,
        int* __restrict__ blksum, int n) {
    __shared__ int sh[SCAN_B];
    int i = blockIdx.x * SCAN_B + threadIdx.x;
    int v = (i < n) ? in[i] : 0;
    sh[threadIdx.x] = v;
    __syncthreads();
    for (int off = 1; off < SCAN_B; off <<= 1) {
        int t = (threadIdx.x >= off) ? sh[threadIdx.x - off] : 0;
        __syncthreads();
        sh[threadIdx.x] += t;
        __syncthreads();
    }
    if (i < n) out[i] = sh[threadIdx.x] - v;
    if (threadIdx.x == SCAN_B - 1) blksum[blockIdx.x] = sh[SCAN_B - 1];
}

// ---------------------------------------------------------------------------
// scan step B: single-block exclusive scan of block sums
// ---------------------------------------------------------------------------
__global__ __launch_bounds__(SCAN_B) void scan_top_kernel(int* __restrict__ blksum,
                                                          int nblk) {
    __shared__ int sh[SCAN_B];
    int v = (threadIdx.x < nblk) ? blksum[threadIdx.x] : 0;
    sh[threadIdx.x] = v;
    __syncthreads();
    for (int off = 1; off < SCAN_B; off <<= 1) {
        int t = (threadIdx.x >= off) ? sh[threadIdx.x - off] : 0;
        __syncthreads();
        sh[threadIdx.x] += t;
        __syncthreads();
    }
    if (threadIdx.x < nblk) blksum[threadIdx.x] = sh[threadIdx.x] - v;
}

// ---------------------------------------------------------------------------
// scan step C: add block offsets (in place)
// ---------------------------------------------------------------------------
__global__ void scan_fix_kernel(int* __restrict__ out,
                                const int* __restrict__ blksum, int n) {
    int i = blockIdx.x * blockDim.x + threadIdx.x;
    if (i < n) out[i] += blksum[i / SCAN_B];
}

// ---------------------------------------------------------------------------
// scatter: WG wg re-reads its chunk; positions come from LDS cursors seeded
// with the scanned per-(bucket,wg) bases. ZERO global atomics.
// payload: w0 = (row8 << 18) | col  (row8 = row % 240 < 256, col < 2^18)
//          w1 = val (fp32 bits)
// ---------------------------------------------------------------------------
__global__ __launch_bounds__(256) void scatter_lds_kernel(
        const int* __restrict__ rows,
        const int* __restrict__ cols,
        const float* __restrict__ vals,
        const int* __restrict__ baseArr,
        int2* __restrict__ ebuf) {
    __shared__ int cur[NBUCK];
    for (int k = threadIdx.x; k < NBUCK; k += 256)
        cur[k] = baseArr[k * NWG + blockIdx.x];
    __syncthreads();
    int lo = blockIdx.x * CHUNK, hi = min(NNZ, lo + CHUNK);
    for (int e = lo + threadIdx.x; e < hi; e += 256) {
        int   r = rows[e];
        int   c = cols[e];
        float v = vals[e];
        int   b = r / BROWS;
        int pos = atomicAdd(&cur[b], 1);        // LDS atomic (ds_add_rtn)
        ebuf[pos] = make_int2(((r - b * BROWS) << 18) | c, __float_as_int(v));
    }
}

// ---------------------------------------------------------------------------
// convert: xb = bf16(concat(user_emb, item_emb)), vectorized
// ---------------------------------------------------------------------------
__global__ void convert_kernel(const float* __restrict__ user_emb,
                               const float* __restrict__ item_emb,
                               ushort* __restrict__ xb) {
    const int64_t total4 = (int64_t)N_NODES * DIM / 4;
    const int64_t user4  = (int64_t)NUM_USERS * DIM / 4;
    int64_t stride = (int64_t)gridDim.x * blockDim.x;
    for (int64_t i = (int64_t)blockIdx.x * blockDim.x + threadIdx.x;
         i < total4; i += stride) {
        float4 v = (i < user4) ? ((const float4*)user_emb)[i]
                               : ((const float4*)item_emb)[i - user4];
        ushort4 o;
        o.x = f2bf(v.x); o.y = f2bf(v.y); o.z = f2bf(v.z); o.w = f2bf(v.w);
        ((ushort4*)xb)[i] = o;
    }
}

// ---------------------------------------------------------------------------
// bitmap: flag rows gathered by the batch (for the filtered last layer)
// ---------------------------------------------------------------------------
__global__ void bitmap_kernel(const int* __restrict__ user_idx,
                              const int* __restrict__ item_idx,
                              uint32* __restrict__ bm) {
    int i = blockIdx.x * blockDim.x + threadIdx.x;
    if (i < 2 * BATCH) {
        int row = (i < BATCH) ? user_idx[i] : (NUM_USERS + item_idx[i - BATCH]);
        atomicOr(&bm[row >> 5], 1u << (row & 31));
    }
}

// ---------------------------------------------------------------------------
// SpMM via LDS accumulation: one WG per 240-row bucket, 61.4 KB fp32 LDS acc
// (2 WGs/CU). Each wave: coalesced int2 load of 64 edges, readlane-broadcast
// each edge, gather x-row (64 lanes), ds_add_f32 into acc (2-way bank: free).
// FILTER: skip edges whose output row isn't in the batch bitmap (uniform
// scalar branch, since row8 is wave-uniform).
// ---------------------------------------------------------------------------
template <bool FILTER>
__global__ __launch_bounds__(256) void spmm_lds_kernel(
        const int* __restrict__ baseArr,
        const int2* __restrict__ ebuf,
        const ushort* __restrict__ xin,
        const uint32* __restrict__ bitmap,
        ushort* __restrict__ yout) {
    __shared__ float accs[BROWS * DIM];          // 61440 B
    __shared__ uint32 bm[10];
    const int b    = blockIdx.x;
    const int tid  = threadIdx.x;
    const int lane = tid & 63;
    const int wv   = tid >> 6;

    const int start = baseArr[b * NWG];
    const int end   = (b == NBUCK - 1) ? NNZ : baseArr[(b + 1) * NWG];

    for (int k = tid; k < BROWS * DIM; k += 256) accs[k] = 0.f;
    int bitoff = 0;
    if (FILTER) {
        int bit0 = b * BROWS;
        bitoff = bit0 & 31;
        if (tid < 9)  bm[tid] = bitmap[(bit0 >> 5) + tid];
        if (tid == 9) bm[9] = 0;
    }
    __syncthreads();

    for (int cb = start + wv * 64; cb < end; cb += 256) {
        int idx     = cb + lane;
        int clamped = min(idx, end - 1);
        int2 p = ebuf[clamped];
        float val = (idx < end) ? __int_as_float(p.y) : 0.f;
        int   w0  = p.x;
        #pragma unroll
        for (int t = 0; t < 64; ++t) {
            int   w0t = __builtin_amdgcn_readlane(w0, t);
            int   col  = w0t & 0x3FFFF;
            int   row8 = w0t >> 18;                     // wave-uniform
            if (FILTER) {
                int bit = bitoff + row8;
                if (!((bm[bit >> 5] >> (bit & 31)) & 1u)) continue;
            }
            float vt = __uint_as_float(
                (uint32)__builtin_amdgcn_readlane((int)__float_as_uint(val), t));
            float xv = bf2f(xin[((int64_t)col << 6) | lane]);
            atomicAdd(&accs[(row8 << 6) | lane], vt * xv);
        }
    }
    __syncthreads();

    const int64_t row0 = (int64_t)b * BROWS;
    for (int k = tid; k < BROWS * DIM; k += 256)
        yout[row0 * DIM + k] = f2bf(accs[k]);
}

// ---------------------------------------------------------------------------
// Per-batch accumulator update: acc[i] (+)= x[row(i)]
// ---------------------------------------------------------------------------
template <bool FIRST>
__global__ void gather_acc_kernel(const int* __restrict__ user_idx,
                                  const int* __restrict__ item_idx,
                                  const ushort* __restrict__ x,
                                  const float* __restrict__ user_emb,
                                  const float* __restrict__ item_emb,
                                  float* __restrict__ acc) {
    const int lane = threadIdx.x & 63;
    const int i = (int)(((uint32)blockIdx.x * blockDim.x + threadIdx.x) >> 6);
    if (i >= 2 * BATCH) return;
    if (FIRST) {
        float v;
        if (i < BATCH) v = user_emb[(int64_t)user_idx[i] * DIM + lane];
        else           v = item_emb[(int64_t)item_idx[i - BATCH] * DIM + lane];
        acc[(int64_t)i * DIM + lane] = v;
    } else {
        int row = (i < BATCH) ? user_idx[i] : (NUM_USERS + item_idx[i - BATCH]);
        acc[(int64_t)i * DIM + lane] += bf2f(x[(int64_t)row * DIM + lane]);
    }
}

// ---------------------------------------------------------------------------
// Output: rating dot + scaled user/item embeddings
// ---------------------------------------------------------------------------
__global__ void out_kernel(const float* __restrict__ acc, float* __restrict__ out) {
    const int lane = threadIdx.x & 63;
    const int b = (int)(((uint32)blockIdx.x * blockDim.x + threadIdx.x) >> 6);
    if (b >= BATCH) return;
    float uv = acc[(int64_t)b * DIM + lane] * 0.25f;
    float iv = acc[(int64_t)(BATCH + b) * DIM + lane] * 0.25f;
    out[(int64_t)BATCH + (int64_t)b * DIM + lane] = uv;
    out[(int64_t)BATCH + (int64_t)BATCH * DIM + (int64_t)b * DIM + lane] = iv;
    float p = uv * iv;
    #pragma unroll
    for (int off = 32; off >= 1; off >>= 1) p += __shfl_down(p, off, 64);
    if (lane == 0) out[b] = p;
}

// ---------------------------------------------------------------------------
extern "C" void kernel_launch(void* const* d_in, const int* in_sizes, int n_in,
                              void* d_out, int out_size, void* d_ws, size_t ws_size,
                              hipStream_t stream) {
    const int*   user_idx = (const int*)  d_in[0];
    const int*   item_idx = (const int*)  d_in[1];
    const int*   rows     = (const int*)  d_in[2];
    const int*   cols     = (const int*)  d_in[3];
    const float* vals     = (const float*)d_in[4];
    const float* user_emb = (const float*)d_in[5];
    const float* item_emb = (const float*)d_in[6];
    float*       out      = (float*)d_out;

    // ---- workspace layout ----
    char* base = (char*)d_ws;
    size_t off = 0;
    auto alloc = [&](size_t bytes) -> char* {
        char* p = base + off;
        off = (off + bytes + 255) & ~(size_t)255;
        return p;
    };
    int*    cntArr  = (int*)   alloc((size_t)SCAN_N * sizeof(int));
    int*    baseArr = (int*)   alloc((size_t)SCAN_N * sizeof(int));
    int*    blksum  = (int*)   alloc((size_t)(NBLK_S + 1) * sizeof(int));
    int2*   ebuf    = (int2*)  alloc((size_t)NNZ * sizeof(int2));
    uint32* bm      = (uint32*)alloc((size_t)4704 * sizeof(uint32));
    ushort* xb      = (ushort*)alloc((size_t)N_NODES * DIM * sizeof(ushort));
    ushort* buf0    = (ushort*)alloc((size_t)N_NODES * DIM * sizeof(ushort));
    ushort* buf1    = (ushort*)alloc((size_t)N_NODES * DIM * sizeof(ushort));
    float*  acc     = (float*) alloc((size_t)2 * BATCH * DIM * sizeof(float));

    const int TB = 256;

    // ---- batch-row bitmap (independent) ----
    hipMemsetAsync(bm, 0, (size_t)4704 * sizeof(uint32), stream);
    bitmap_kernel<<<(2 * BATCH + TB - 1) / TB, TB, 0, stream>>>(user_idx, item_idx, bm);

    // ---- bucket-grouped edge build: count -> scan -> scatter ----
    count_kernel<<<NWG, TB, 0, stream>>>(rows, cntArr);
    scan_block_kernel<<<NBLK_S, SCAN_B, 0, stream>>>(cntArr, baseArr, blksum, SCAN_N);
    scan_top_kernel<<<1, SCAN_B, 0, stream>>>(blksum, NBLK_S);
    scan_fix_kernel<<<(SCAN_N + TB - 1) / TB, TB, 0, stream>>>(baseArr, blksum, SCAN_N);
    scatter_lds_kernel<<<NWG, TB, 0, stream>>>(rows, cols, vals, baseArr, ebuf);

    // ---- bf16 node features ----
    convert_kernel<<<2048, TB, 0, stream>>>(user_emb, item_emb, xb);

    // ---- propagation ----
    const int gathBlocks = (2 * BATCH * 64 + TB - 1) / TB;

    gather_acc_kernel<true><<<gathBlocks, TB, 0, stream>>>(
        user_idx, item_idx, nullptr, user_emb, item_emb, acc);

    spmm_lds_kernel<false><<<NBUCK, TB, 0, stream>>>(baseArr, ebuf, xb, nullptr, buf0);
    gather_acc_kernel<false><<<gathBlocks, TB, 0, stream>>>(
        user_idx, item_idx, buf0, nullptr, nullptr, acc);

    spmm_lds_kernel<false><<<NBUCK, TB, 0, stream>>>(baseArr, ebuf, buf0, nullptr, buf1);
    gather_acc_kernel<false><<<gathBlocks, TB, 0, stream>>>(
        user_idx, item_idx, buf1, nullptr, nullptr, acc);

    spmm_lds_kernel<true><<<NBUCK, TB, 0, stream>>>(baseArr, ebuf, buf1, bm, buf0);
    gather_acc_kernel<false><<<gathBlocks, TB, 0, stream>>>(
        user_idx, item_idx, buf0, nullptr, nullptr, acc);

    // ---- output ----
    out_kernel<<<(BATCH * 64 + TB - 1) / TB, TB, 0, stream>>>(acc, out);
}

// Round 7
// 167.565 us; speedup vs baseline: 6.0323x; 6.0323x over previous
//
#include <hip/hip_runtime.h>

#define NUM_USERS 100000
#define NUM_ITEMS 50000
#define N_NODES   150000   // NUM_USERS + NUM_ITEMS
#define DIM       64
#define NNZ       1000000
#define BATCH     4096

#define BROWS  240                    // rows per bucket (625 * 240 == 150000)
#define NBUCK  (N_NODES / BROWS)      // 625
#define NWG    256                    // workgroups in count/scatter
#define CHUNK  ((NNZ + NWG - 1) / NWG)// 3907 edges per WG
#define SCAN_N (NBUCK * NWG)          // 160000
#define SCAN_B 512
#define NBLK_S ((SCAN_N + SCAN_B - 1) / SCAN_B)  // 313

typedef unsigned int uint32;

// bf16 helpers (RNE convert, cheap expand)
__device__ __forceinline__ ushort f2bf(float f) {
    uint32 u = __float_as_uint(f);
    u += 0x7FFFu + ((u >> 16) & 1u);
    return (ushort)(u >> 16);
}
__device__ __forceinline__ float bf2f(ushort u) {
    return __uint_as_float(((uint32)u) << 16);
}

// ---------------------------------------------------------------------------
// count: per-WG histogram of bucket occupancy. cntArr[b*NWG + wg] (bucket-
// major so the flat exclusive scan yields segment bases directly).
// ---------------------------------------------------------------------------
__global__ __launch_bounds__(256) void count_kernel(const int* __restrict__ rows,
                                                    int* __restrict__ cntArr) {
    __shared__ int h[NBUCK];
    for (int k = threadIdx.x; k < NBUCK; k += 256) h[k] = 0;
    __syncthreads();
    int lo = blockIdx.x * CHUNK, hi = min(NNZ, lo + CHUNK);
    for (int e = lo + threadIdx.x; e < hi; e += 256)
        atomicAdd(&h[__builtin_nontemporal_load(&rows[e]) / BROWS], 1);
    __syncthreads();
    for (int k = threadIdx.x; k < NBUCK; k += 256)
        cntArr[k * NWG + blockIdx.x] = h[k];
}

// ---------------------------------------------------------------------------
// scan step A: per-block exclusive scan (512/block); blksum <- block total
// ---------------------------------------------------------------------------
__global__ __launch_bounds__(SCAN_B) void scan_block_kernel(
        const int* __restrict__ in, int* __restrict__ out,
        int* __restrict__ blksum, int n) {
    __shared__ int sh[SCAN_B];
    int i = blockIdx.x * SCAN_B + threadIdx.x;
    int v = (i < n) ? in[i] : 0;
    sh[threadIdx.x] = v;
    __syncthreads();
    for (int off = 1; off < SCAN_B; off <<= 1) {
        int t = (threadIdx.x >= off) ? sh[threadIdx.x - off] : 0;
        __syncthreads();
        sh[threadIdx.x] += t;
        __syncthreads();
    }
    if (i < n) out[i] = sh[threadIdx.x] - v;
    if (threadIdx.x == SCAN_B - 1) blksum[blockIdx.x] = sh[SCAN_B - 1];
}

// ---------------------------------------------------------------------------
// scan step B: single-block exclusive scan of block sums
// ---------------------------------------------------------------------------
__global__ __launch_bounds__(SCAN_B) void scan_top_kernel(int* __restrict__ blksum,
                                                          int nblk) {
    __shared__ int sh[SCAN_B];
    int v = (threadIdx.x < nblk) ? blksum[threadIdx.x] : 0;
    sh[threadIdx.x] = v;
    __syncthreads();
    for (int off = 1; off < SCAN_B; off <<= 1) {
        int t = (threadIdx.x >= off) ? sh[threadIdx.x - off] : 0;
        __syncthreads();
        sh[threadIdx.x] += t;
        __syncthreads();
    }
    if (threadIdx.x < nblk) blksum[threadIdx.x] = sh[threadIdx.x] - v;
}

// ---------------------------------------------------------------------------
// scan step C: add block offsets (in place); also set rowptr[N_NODES]=NNZ
// ---------------------------------------------------------------------------
__global__ void scan_fix_kernel(int* __restrict__ out,
                                const int* __restrict__ blksum, int n,
                                int* __restrict__ rowptr) {
    int i = blockIdx.x * blockDim.x + threadIdx.x;
    if (i < n) out[i] += blksum[i / SCAN_B];
    if (i == 0) rowptr[N_NODES] = NNZ;
}

// ---------------------------------------------------------------------------
// scatter: WG wg re-reads its chunk; positions from LDS cursors seeded with
// scanned per-(bucket,wg) bases. ZERO global atomics.
// payload: w0 = (row8 << 18) | col  (row8 < 240, col < 2^18)
// ---------------------------------------------------------------------------
__global__ __launch_bounds__(256) void scatter_lds_kernel(
        const int* __restrict__ rows,
        const int* __restrict__ cols,
        const float* __restrict__ vals,
        const int* __restrict__ baseArr,
        int2* __restrict__ ebuf) {
    __shared__ int cur[NBUCK];
    for (int k = threadIdx.x; k < NBUCK; k += 256)
        cur[k] = baseArr[k * NWG + blockIdx.x];
    __syncthreads();
    int lo = blockIdx.x * CHUNK, hi = min(NNZ, lo + CHUNK);
    for (int e = lo + threadIdx.x; e < hi; e += 256) {
        int   r = __builtin_nontemporal_load(&rows[e]);
        int   c = __builtin_nontemporal_load(&cols[e]);
        float v = __builtin_nontemporal_load(&vals[e]);
        int   b = r / BROWS;
        int pos = atomicAdd(&cur[b], 1);        // LDS atomic
        ebuf[pos] = make_int2(((r - b * BROWS) << 18) | c, __float_as_int(v));
    }
}

// ---------------------------------------------------------------------------
// localsort: one WG per bucket. Pass 1 counts rows (LDS), scan in LDS,
// pass 2 scatters bucket-local edges into exact CSR order in ebuf2 and
// writes the rowptr segment. All positions from LDS cursors.
// ---------------------------------------------------------------------------
__global__ __launch_bounds__(256) void localsort_kernel(
        const int* __restrict__ baseArr,
        const int2* __restrict__ ebuf,
        int2* __restrict__ ebuf2,
        int* __restrict__ rowptr) {
    __shared__ int cnt[BROWS];
    __shared__ int cur[BROWS];
    __shared__ int sh[256];
    const int b = blockIdx.x;
    const int start = baseArr[b * NWG];
    const int end   = (b == NBUCK - 1) ? NNZ : baseArr[(b + 1) * NWG];

    for (int k = threadIdx.x; k < BROWS; k += 256) cnt[k] = 0;
    __syncthreads();
    for (int e = start + threadIdx.x; e < end; e += 256)
        atomicAdd(&cnt[ebuf[e].x >> 18], 1);
    __syncthreads();

    int v = (threadIdx.x < BROWS) ? cnt[threadIdx.x] : 0;
    sh[threadIdx.x] = v;
    __syncthreads();
    for (int off = 1; off < 256; off <<= 1) {
        int t = (threadIdx.x >= off) ? sh[threadIdx.x - off] : 0;
        __syncthreads();
        sh[threadIdx.x] += t;
        __syncthreads();
    }
    if (threadIdx.x < BROWS) {
        int p = start + sh[threadIdx.x] - v;    // exclusive
        cur[threadIdx.x] = p;
        rowptr[b * BROWS + threadIdx.x] = p;
    }
    __syncthreads();

    for (int e = start + threadIdx.x; e < end; e += 256) {
        int2 p = ebuf[e];
        int row8 = p.x >> 18;
        int col  = p.x & 0x3FFFF;
        int pos = atomicAdd(&cur[row8], 1);
        ebuf2[pos] = make_int2(col, p.y);
    }
}

// ---------------------------------------------------------------------------
// convert: xb = bf16(concat(user_emb, item_emb)), vectorized
// ---------------------------------------------------------------------------
__global__ void convert_kernel(const float* __restrict__ user_emb,
                               const float* __restrict__ item_emb,
                               ushort* __restrict__ xb) {
    const int64_t total4 = (int64_t)N_NODES * DIM / 4;
    const int64_t user4  = (int64_t)NUM_USERS * DIM / 4;
    int64_t stride = (int64_t)gridDim.x * blockDim.x;
    for (int64_t i = (int64_t)blockIdx.x * blockDim.x + threadIdx.x;
         i < total4; i += stride) {
        float4 v = (i < user4) ? ((const float4*)user_emb)[i]
                               : ((const float4*)item_emb)[i - user4];
        ushort4 o;
        o.x = f2bf(v.x); o.y = f2bf(v.y); o.z = f2bf(v.z); o.w = f2bf(v.w);
        ((ushort4*)xb)[i] = o;
    }
}

// ---------------------------------------------------------------------------
// SpMM (CSR, bf16): one wave per 8 rows, lane = dim, branch-free chains.
// (round-5 proven structure)
// ---------------------------------------------------------------------------
__global__ __launch_bounds__(256) void spmm8_kernel(
        const int* __restrict__ rowptr,
        const int2* __restrict__ edges,
        const ushort* __restrict__ xin,
        ushort* __restrict__ yout) {
    const int lane = threadIdx.x & 63;
    const int w = (int)(((uint32)blockIdx.x * blockDim.x + threadIdx.x) >> 6);
    const int r0 = w * 8;
    if (r0 >= N_NODES) return;

    int rp[9];
    #pragma unroll
    for (int j = 0; j < 9; ++j) rp[j] = rowptr[r0 + j];

    int e[8], end[8];
    int trips = 0;
    #pragma unroll
    for (int j = 0; j < 8; ++j) {
        e[j] = rp[j]; end[j] = rp[j + 1];
        trips = max(trips, end[j] - e[j]);
    }
    float acc[8] = {0.f, 0.f, 0.f, 0.f, 0.f, 0.f, 0.f, 0.f};

    for (int t = 0; t < trips; ++t) {
        int   col[8];
        float val[8];
        #pragma unroll
        for (int j = 0; j < 8; ++j) {
            bool act = e[j] < end[j];
            int idx  = __builtin_amdgcn_readfirstlane(act ? e[j] : 0);
            int2 ed  = edges[idx];
            col[j] = __builtin_amdgcn_readfirstlane(ed.x);
            val[j] = act ? __int_as_float(ed.y) : 0.f;
            e[j]  += act ? 1 : 0;
        }
        #pragma unroll
        for (int j = 0; j < 8; ++j) {
            float xv = bf2f(xin[(int64_t)col[j] * DIM + lane]);
            acc[j] = fmaf(val[j], xv, acc[j]);
        }
    }
    #pragma unroll
    for (int j = 0; j < 8; ++j)
        yout[(int64_t)(r0 + j) * DIM + lane] = f2bf(acc[j]);
}

// ---------------------------------------------------------------------------
// Layer-3 SpMM restricted to the 8192 batch rows, fused with acc update.
// ---------------------------------------------------------------------------
__global__ __launch_bounds__(256) void spmm_batch_kernel(
        const int* __restrict__ user_idx,
        const int* __restrict__ item_idx,
        const int* __restrict__ rowptr,
        const int2* __restrict__ edges,
        const ushort* __restrict__ xin,
        float* __restrict__ acc) {
    const int lane = threadIdx.x & 63;
    const int w = (int)(((uint32)blockIdx.x * blockDim.x + threadIdx.x) >> 6);
    const int i0 = w * 8;
    if (i0 >= 2 * BATCH) return;

    int e[8], end[8];
    int trips = 0;
    #pragma unroll
    for (int j = 0; j < 8; ++j) {
        int i = i0 + j;
        int row = (i < BATCH) ? user_idx[i] : (NUM_USERS + item_idx[i - BATCH]);
        e[j]   = rowptr[row];
        end[j] = rowptr[row + 1];
        trips = max(trips, end[j] - e[j]);
    }
    float a[8] = {0.f, 0.f, 0.f, 0.f, 0.f, 0.f, 0.f, 0.f};

    for (int t = 0; t < trips; ++t) {
        int   col[8];
        float val[8];
        #pragma unroll
        for (int j = 0; j < 8; ++j) {
            bool act = e[j] < end[j];
            int idx  = __builtin_amdgcn_readfirstlane(act ? e[j] : 0);
            int2 ed  = edges[idx];
            col[j] = __builtin_amdgcn_readfirstlane(ed.x);
            val[j] = act ? __int_as_float(ed.y) : 0.f;
            e[j]  += act ? 1 : 0;
        }
        #pragma unroll
        for (int j = 0; j < 8; ++j) {
            float xv = bf2f(xin[(int64_t)col[j] * DIM + lane]);
            a[j] = fmaf(val[j], xv, a[j]);
        }
    }
    #pragma unroll
    for (int j = 0; j < 8; ++j)
        acc[(int64_t)(i0 + j) * DIM + lane] += a[j];
}

// ---------------------------------------------------------------------------
// Per-batch accumulator update: acc[i] (+)= x[row(i)]
// ---------------------------------------------------------------------------
template <bool FIRST>
__global__ void gather_acc_kernel(const int* __restrict__ user_idx,
                                  const int* __restrict__ item_idx,
                                  const ushort* __restrict__ x,
                                  const float* __restrict__ user_emb,
                                  const float* __restrict__ item_emb,
                                  float* __restrict__ acc) {
    const int lane = threadIdx.x & 63;
    const int i = (int)(((uint32)blockIdx.x * blockDim.x + threadIdx.x) >> 6);
    if (i >= 2 * BATCH) return;
    if (FIRST) {
        float v;
        if (i < BATCH) v = user_emb[(int64_t)user_idx[i] * DIM + lane];
        else           v = item_emb[(int64_t)item_idx[i - BATCH] * DIM + lane];
        acc[(int64_t)i * DIM + lane] = v;
    } else {
        int row = (i < BATCH) ? user_idx[i] : (NUM_USERS + item_idx[i - BATCH]);
        acc[(int64_t)i * DIM + lane] += bf2f(x[(int64_t)row * DIM + lane]);
    }
}

// ---------------------------------------------------------------------------
// Output: rating dot + scaled user/item embeddings
// ---------------------------------------------------------------------------
__global__ void out_kernel(const float* __restrict__ acc, float* __restrict__ out) {
    const int lane = threadIdx.x & 63;
    const int b = (int)(((uint32)blockIdx.x * blockDim.x + threadIdx.x) >> 6);
    if (b >= BATCH) return;
    float uv = acc[(int64_t)b * DIM + lane] * 0.25f;
    float iv = acc[(int64_t)(BATCH + b) * DIM + lane] * 0.25f;
    out[(int64_t)BATCH + (int64_t)b * DIM + lane] = uv;
    out[(int64_t)BATCH + (int64_t)BATCH * DIM + (int64_t)b * DIM + lane] = iv;
    float p = uv * iv;
    #pragma unroll
    for (int off = 32; off >= 1; off >>= 1) p += __shfl_down(p, off, 64);
    if (lane == 0) out[b] = p;
}

// ---------------------------------------------------------------------------
extern "C" void kernel_launch(void* const* d_in, const int* in_sizes, int n_in,
                              void* d_out, int out_size, void* d_ws, size_t ws_size,
                              hipStream_t stream) {
    const int*   user_idx = (const int*)  d_in[0];
    const int*   item_idx = (const int*)  d_in[1];
    const int*   rows     = (const int*)  d_in[2];
    const int*   cols     = (const int*)  d_in[3];
    const float* vals     = (const float*)d_in[4];
    const float* user_emb = (const float*)d_in[5];
    const float* item_emb = (const float*)d_in[6];
    float*       out      = (float*)d_out;

    // ---- workspace layout ----
    char* base = (char*)d_ws;
    size_t off = 0;
    auto alloc = [&](size_t bytes) -> char* {
        char* p = base + off;
        off = (off + bytes + 255) & ~(size_t)255;
        return p;
    };
    int*    cntArr  = (int*)   alloc((size_t)SCAN_N * sizeof(int));
    int*    baseArr = (int*)   alloc((size_t)SCAN_N * sizeof(int));
    int*    blksum  = (int*)   alloc((size_t)(NBLK_S + 1) * sizeof(int));
    int*    rowptr  = (int*)   alloc((size_t)(N_NODES + 1) * sizeof(int));
    int2*   ebuf    = (int2*)  alloc((size_t)NNZ * sizeof(int2));
    int2*   ebuf2   = (int2*)  alloc((size_t)NNZ * sizeof(int2));
    ushort* xb      = (ushort*)alloc((size_t)N_NODES * DIM * sizeof(ushort));
    ushort* buf0    = (ushort*)alloc((size_t)N_NODES * DIM * sizeof(ushort));
    ushort* buf1    = (ushort*)alloc((size_t)N_NODES * DIM * sizeof(ushort));
    float*  acc     = (float*) alloc((size_t)2 * BATCH * DIM * sizeof(float));

    const int TB = 256;

    // ---- bucket-grouped edge build -> exact CSR (no global atomics) ----
    count_kernel<<<NWG, TB, 0, stream>>>(rows, cntArr);
    scan_block_kernel<<<NBLK_S, SCAN_B, 0, stream>>>(cntArr, baseArr, blksum, SCAN_N);
    scan_top_kernel<<<1, SCAN_B, 0, stream>>>(blksum, NBLK_S);
    scan_fix_kernel<<<(SCAN_N + TB - 1) / TB, TB, 0, stream>>>(baseArr, blksum, SCAN_N, rowptr);
    scatter_lds_kernel<<<NWG, TB, 0, stream>>>(rows, cols, vals, baseArr, ebuf);
    localsort_kernel<<<NBUCK, TB, 0, stream>>>(baseArr, ebuf, ebuf2, rowptr);

    // ---- bf16 node features ----
    convert_kernel<<<2048, TB, 0, stream>>>(user_emb, item_emb, xb);

    // ---- propagation ----
    const int spmmBlocks = (N_NODES / 8 * 64 + TB - 1) / TB;   // 8 rows per wave
    const int gathBlocks = (2 * BATCH * 64 + TB - 1) / TB;
    const int batchBlocks = (2 * BATCH / 8 * 64 + TB - 1) / TB;

    gather_acc_kernel<true><<<gathBlocks, TB, 0, stream>>>(
        user_idx, item_idx, nullptr, user_emb, item_emb, acc);

    // layer 1: xb -> buf0 ; acc += l1
    spmm8_kernel<<<spmmBlocks, TB, 0, stream>>>(rowptr, ebuf2, xb, buf0);
    gather_acc_kernel<false><<<gathBlocks, TB, 0, stream>>>(
        user_idx, item_idx, buf0, nullptr, nullptr, acc);

    // layer 2: buf0 -> buf1 ; acc += l2
    spmm8_kernel<<<spmmBlocks, TB, 0, stream>>>(rowptr, ebuf2, buf0, buf1);
    gather_acc_kernel<false><<<gathBlocks, TB, 0, stream>>>(
        user_idx, item_idx, buf1, nullptr, nullptr, acc);

    // layer 3: batch rows only, fused into acc
    spmm_batch_kernel<<<batchBlocks, TB, 0, stream>>>(
        user_idx, item_idx, rowptr, ebuf2, buf1, acc);

    // ---- output ----
    out_kernel<<<(BATCH * 64 + TB - 1) / TB, TB, 0, stream>>>(acc, out);
}